// Round 1
// baseline (221.753 us; speedup 1.0000x reference)
//
#include <hip/hip_runtime.h>
#include <hip/hip_bf16.h>
#include <math.h>

typedef __bf16  bf16x8 __attribute__((ext_vector_type(8)));
typedef float   f32x4  __attribute__((ext_vector_type(4)));

// ---------------- helpers ----------------
static __device__ __forceinline__ void load_lds16(const void* g, void* l) {
  __builtin_amdgcn_global_load_lds(
      (const __attribute__((address_space(1))) void*)(g),
      (__attribute__((address_space(3))) void*)(l), 16, 0, 0);
}

// ---- K_t: t = WHT_2048(BB_w[:2048] * z); zero Sw accumulator ----
__global__ __launch_bounds__(256) void k_t(const float* __restrict__ z,
                                           const float* __restrict__ BBw,
                                           float* __restrict__ t_out,
                                           float* __restrict__ Sw) {
  __shared__ float u[2048];
  const int tid = threadIdx.x;
  for (int i = tid; i < 2048; i += 256) u[i] = BBw[i] * z[i];
  __syncthreads();
  for (int len = 1; len < 2048; len <<= 1) {
    #pragma unroll
    for (int q = 0; q < 4; ++q) {
      int j = q * 256 + tid;
      int a = ((j & ~(len - 1)) << 1) | (j & (len - 1));
      float x = u[a], y = u[a + len];
      u[a] = x + y; u[a + len] = x - y;
    }
    __syncthreads();
  }
  for (int i = tid; i < 2048; i += 256) t_out[i] = u[i];
  if (tid == 0) *Sw = 0.0f;
}

// ---- K_bias: full 4096-point fastfood for bias; bout = b0 + db ----
__global__ __launch_bounds__(1024) void k_bias(const float* __restrict__ z,
                                               const float* __restrict__ b0,
                                               const float* __restrict__ BBb,
                                               const float* __restrict__ GGb,
                                               const int* __restrict__ Pib,
                                               float* __restrict__ bout) {
  __shared__ float m1[4096];
  __shared__ float m2[4096];
  __shared__ float red[16];
  const int tid = threadIdx.x;
  for (int i = tid; i < 4096; i += 1024)
    m1[i] = (i < 2048) ? BBb[i] * z[i] : 0.0f;
  float s = 0.0f;
  for (int i = tid; i < 4096; i += 1024) { float g = GGb[i]; s += g * g; }
  for (int off = 32; off > 0; off >>= 1) s += __shfl_down(s, off);
  if ((tid & 63) == 0) red[tid >> 6] = s;
  __syncthreads();
  for (int len = 1; len < 4096; len <<= 1) {
    #pragma unroll
    for (int q = 0; q < 2; ++q) {
      int j = q * 1024 + tid;
      int a = ((j & ~(len - 1)) << 1) | (j & (len - 1));
      float x = m1[a], y = m1[a + len];
      m1[a] = x + y; m1[a + len] = x - y;
    }
    __syncthreads();
  }
  for (int i = tid; i < 4096; i += 1024) m2[i] = m1[Pib[i]] * GGb[i];
  __syncthreads();
  for (int len = 1; len < 4096; len <<= 1) {
    #pragma unroll
    for (int q = 0; q < 2; ++q) {
      int j = q * 1024 + tid;
      int a = ((j & ~(len - 1)) << 1) | (j & (len - 1));
      float x = m2[a], y = m2[a + len];
      m2[a] = x + y; m2[a + len] = x - y;
    }
    __syncthreads();
  }
  float Sb = 0.0f;
  #pragma unroll
  for (int i = 0; i < 16; ++i) Sb += red[i];
  const float scale = 1.0f / sqrtf(Sb * 4096.0f);
  for (int i = tid; i < 4096; i += 1024) bout[i] = b0[i] + m2[i] * scale;
}

// ---- K1: per-row gather (t LDS table) + WHT_2048 along f; Sw atomic ----
__global__ __launch_bounds__(256) void k_gather_pass1(const float* __restrict__ t,
                                                      const int* __restrict__ Piw,
                                                      const float* __restrict__ GGw,
                                                      float* __restrict__ mout,
                                                      float* __restrict__ Sw) {
  __shared__ float tl[2048];
  __shared__ float row[2048];
  __shared__ float red[4];
  const int tid = threadIdx.x;
  const size_t p0 = (size_t)blockIdx.x * 2048;
  for (int i = tid; i < 2048; i += 256) tl[i] = t[i];
  __syncthreads();
  float s = 0.0f;
  #pragma unroll
  for (int q = 0; q < 8; ++q) {
    int i = q * 256 + tid;
    int pi = Piw[p0 + i];
    float g = GGw[p0 + i];
    row[i] = tl[pi & 2047] * g;
    s += g * g;
  }
  for (int off = 32; off > 0; off >>= 1) s += __shfl_down(s, off);
  if ((tid & 63) == 0) red[tid >> 6] = s;
  __syncthreads();
  if (tid == 0) atomicAdd(Sw, red[0] + red[1] + red[2] + red[3]);
  for (int len = 1; len < 2048; len <<= 1) {
    #pragma unroll
    for (int q = 0; q < 4; ++q) {
      int j = q * 256 + tid;
      int a = ((j & ~(len - 1)) << 1) | (j & (len - 1));
      float x = row[a], y = row[a + len];
      row[a] = x + y; row[a + len] = x - y;
    }
    __syncthreads();
  }
  for (int i = tid; i < 2048; i += 256) mout[p0 + i] = row[i];
}

// ---- K2a: in-register WHT_64 over o_lo (stride 2048 floats) ----
__global__ __launch_bounds__(256) void k_pass2a(float* __restrict__ m) {
  const int tg = blockIdx.x * 256 + threadIdx.x;
  const int f = tg & 2047;
  const int oh = tg >> 11;
  const size_t base = (size_t)oh * 131072 + (size_t)f;
  float v[64];
  #pragma unroll
  for (int s = 0; s < 64; ++s) v[s] = m[base + (size_t)s * 2048];
  #pragma unroll
  for (int len = 1; len < 64; len <<= 1) {
    #pragma unroll
    for (int j = 0; j < 32; ++j) {
      int a = ((j & ~(len - 1)) << 1) | (j & (len - 1));
      float x = v[a], y = v[a + len];
      v[a] = x + y; v[a + len] = x - y;
    }
  }
  #pragma unroll
  for (int s = 0; s < 64; ++s) m[base + (size_t)s * 2048] = v[s];
}

// ---- K2b: WHT_64 over o_hi (stride 131072) + epilogue W=bf16(W0+scale*m) ----
__global__ __launch_bounds__(256) void k_pass2b_epi(const float* __restrict__ m,
                                                    const float* __restrict__ W0,
                                                    const float* __restrict__ Sw,
                                                    __hip_bfloat16* __restrict__ Wb) {
  const int tg = blockIdx.x * 256 + threadIdx.x;
  const int f = tg & 2047;
  const int ol = tg >> 11;
  const size_t base = (size_t)ol * 2048 + (size_t)f;
  float v[64];
  #pragma unroll
  for (int s = 0; s < 64; ++s) v[s] = m[base + (size_t)s * 131072];
  #pragma unroll
  for (int len = 1; len < 64; len <<= 1) {
    #pragma unroll
    for (int j = 0; j < 32; ++j) {
      int a = ((j & ~(len - 1)) << 1) | (j & (len - 1));
      float x = v[a], y = v[a + len];
      v[a] = x + y; v[a + len] = x - y;
    }
  }
  const float scale = 1.0f / sqrtf((*Sw) * 8388608.0f);
  #pragma unroll
  for (int s = 0; s < 64; ++s) {
    size_t idx = base + (size_t)s * 131072;
    Wb[idx] = __float2bfloat16(W0[idx] + v[s] * scale);
  }
}

// ---- K_xcast: x (f32) -> bf16 ----
__global__ __launch_bounds__(256) void k_xcast(const float* __restrict__ x,
                                               __hip_bfloat16* __restrict__ xb) {
  const int i = (blockIdx.x * 256 + threadIdx.x) * 4;
  float4 xv = *reinterpret_cast<const float4*>(x + i);
  __hip_bfloat16 h0 = __float2bfloat16(xv.x);
  __hip_bfloat16 h1 = __float2bfloat16(xv.y);
  __hip_bfloat16 h2 = __float2bfloat16(xv.z);
  __hip_bfloat16 h3 = __float2bfloat16(xv.w);
  ushort4 pk = make_ushort4(*reinterpret_cast<unsigned short*>(&h0),
                            *reinterpret_cast<unsigned short*>(&h1),
                            *reinterpret_cast<unsigned short*>(&h2),
                            *reinterpret_cast<unsigned short*>(&h3));
  *reinterpret_cast<ushort4*>(xb + i) = pk;
}

// ---- GEMM: C[4096][4096] = A[4096][2048] * B[4096][2048]^T + bias ----
// m97-style: 128x128 tile, BK=32, 4 waves (2x2), global_load_lds width 16.
__global__ __launch_bounds__(256) void k_gemm(const __hip_bfloat16* __restrict__ A,
                                              const __hip_bfloat16* __restrict__ B,
                                              const float* __restrict__ bias,
                                              float* __restrict__ C) {
  constexpr int K = 2048, N = 4096;
  __shared__ alignas(16) __hip_bfloat16 As[128 * 32];
  __shared__ alignas(16) __hip_bfloat16 Bs[128 * 32];
  const int tid = threadIdx.x;
  const int wave = tid >> 6, lane = tid & 63;
  const int row0 = blockIdx.y * 128, col0 = blockIdx.x * 128;
  const int wm = wave >> 1, wn = wave & 1;
  f32x4 acc[4][4] = {};
  const int srow = (lane >> 2);      // row within 16-row chunk
  const int scol = (lane & 3) * 8;   // bf16 col offset within 32
  for (int k0 = 0; k0 < K; k0 += 32) {
    #pragma unroll
    for (int c = 0; c < 2; ++c) {
      const int chunk = wave + c * 4;           // 0..7, wave-uniform
      const int r = chunk * 16 + srow;
      load_lds16(A + (size_t)(row0 + r) * K + (k0 + scol), As + chunk * 512);
      load_lds16(B + (size_t)(col0 + r) * K + (k0 + scol), Bs + chunk * 512);
    }
    __syncthreads();
    bf16x8 af[4], bfr[4];
    #pragma unroll
    for (int i = 0; i < 4; ++i) {
      af[i]  = *reinterpret_cast<const bf16x8*>(As + (wm * 64 + i * 16 + (lane & 15)) * 32 + (lane >> 4) * 8);
      bfr[i] = *reinterpret_cast<const bf16x8*>(Bs + (wn * 64 + i * 16 + (lane & 15)) * 32 + (lane >> 4) * 8);
    }
    #pragma unroll
    for (int i = 0; i < 4; ++i)
      #pragma unroll
      for (int j = 0; j < 4; ++j)
        acc[i][j] = __builtin_amdgcn_mfma_f32_16x16x32_bf16(af[i], bfr[j], acc[i][j], 0, 0, 0);
    __syncthreads();
  }
  #pragma unroll
  for (int j = 0; j < 4; ++j) {
    const int col = col0 + wn * 64 + j * 16 + (lane & 15);
    const float bv = bias[col];
    #pragma unroll
    for (int i = 0; i < 4; ++i) {
      const int row = row0 + wm * 64 + i * 16 + (lane >> 4) * 4;
      #pragma unroll
      for (int q = 0; q < 4; ++q)
        C[(size_t)(row + q) * N + col] = acc[i][j][q] + bv;
    }
  }
}

extern "C" void kernel_launch(void* const* d_in, const int* in_sizes, int n_in,
                              void* d_out, int out_size, void* d_ws, size_t ws_size,
                              hipStream_t stream) {
  (void)in_sizes; (void)n_in; (void)out_size; (void)ws_size;
  const float* x   = (const float*)d_in[0];
  const float* z   = (const float*)d_in[1];
  const float* W0  = (const float*)d_in[2];
  const float* b0  = (const float*)d_in[3];
  const float* BBw = (const float*)d_in[4];
  const float* GGw = (const float*)d_in[5];
  const float* BBb = (const float*)d_in[6];
  const float* GGb = (const float*)d_in[7];
  const int*   Piw = (const int*)d_in[8];
  const int*   Pib = (const int*)d_in[9];
  float* out = (float*)d_out;

  char* ws = (char*)d_ws;
  float* t_buf = (float*)(ws);                                   // 2048 f
  float* b_buf = (float*)(ws + 8192);                            // 4096 f
  float* Sw    = (float*)(ws + 24576);                           // 1 f
  float* m_buf = (float*)(ws + 32768);                           // 2^23 f (32MB)
  __hip_bfloat16* Wb = (__hip_bfloat16*)(ws + 32768 + 33554432);            // 16MB
  __hip_bfloat16* xb = (__hip_bfloat16*)(ws + 32768 + 33554432 + 16777216); // 16MB

  k_xcast<<<8192, 256, 0, stream>>>(x, xb);
  k_t<<<1, 256, 0, stream>>>(z, BBw, t_buf, Sw);
  k_bias<<<1, 1024, 0, stream>>>(z, b0, BBb, GGb, Pib, b_buf);
  k_gather_pass1<<<4096, 256, 0, stream>>>(t_buf, Piw, GGw, m_buf, Sw);
  k_pass2a<<<512, 256, 0, stream>>>(m_buf);
  k_pass2b_epi<<<512, 256, 0, stream>>>(m_buf, W0, Sw, Wb);
  dim3 g(32, 32);
  k_gemm<<<g, 256, 0, stream>>>(xb, Wb, b_buf, out);
}

// Round 2
// 200.102 us; speedup vs baseline: 1.1082x; 1.1082x over previous
//
#include <hip/hip_runtime.h>
#include <hip/hip_bf16.h>
#include <math.h>

typedef __bf16  bf16x8 __attribute__((ext_vector_type(8)));
typedef float   f32x4  __attribute__((ext_vector_type(4)));

// ---------------- helpers ----------------
static __device__ __forceinline__ void load_lds16(const void* g, void* l) {
  __builtin_amdgcn_global_load_lds(
      (const __attribute__((address_space(1))) void*)(g),
      (__attribute__((address_space(3))) void*)(l), 16, 0, 0);
}

#define BAR() __builtin_amdgcn_s_barrier()
#define LGKM0() do { asm volatile("s_waitcnt lgkmcnt(0)" ::: "memory"); \
                     __builtin_amdgcn_sched_barrier(0); } while (0)
#define VMC(N) asm volatile("s_waitcnt vmcnt(" #N ")" ::: "memory")

// ---- K_t: t = WHT_2048(BB_w[:2048] * z); zero Sw accumulator ----
__global__ __launch_bounds__(256) void k_t(const float* __restrict__ z,
                                           const float* __restrict__ BBw,
                                           float* __restrict__ t_out,
                                           float* __restrict__ Sw) {
  __shared__ float u[2048];
  const int tid = threadIdx.x;
  for (int i = tid; i < 2048; i += 256) u[i] = BBw[i] * z[i];
  __syncthreads();
  for (int len = 1; len < 2048; len <<= 1) {
    #pragma unroll
    for (int q = 0; q < 4; ++q) {
      int j = q * 256 + tid;
      int a = ((j & ~(len - 1)) << 1) | (j & (len - 1));
      float x = u[a], y = u[a + len];
      u[a] = x + y; u[a + len] = x - y;
    }
    __syncthreads();
  }
  for (int i = tid; i < 2048; i += 256) t_out[i] = u[i];
  if (tid == 0) *Sw = 0.0f;
}

// ---- K_bias: full 4096-point fastfood for bias; bout = b0 + db ----
__global__ __launch_bounds__(1024) void k_bias(const float* __restrict__ z,
                                               const float* __restrict__ b0,
                                               const float* __restrict__ BBb,
                                               const float* __restrict__ GGb,
                                               const int* __restrict__ Pib,
                                               float* __restrict__ bout) {
  __shared__ float m1[4096];
  __shared__ float m2[4096];
  __shared__ float red[16];
  const int tid = threadIdx.x;
  for (int i = tid; i < 4096; i += 1024)
    m1[i] = (i < 2048) ? BBb[i] * z[i] : 0.0f;
  float s = 0.0f;
  for (int i = tid; i < 4096; i += 1024) { float g = GGb[i]; s += g * g; }
  for (int off = 32; off > 0; off >>= 1) s += __shfl_down(s, off);
  if ((tid & 63) == 0) red[tid >> 6] = s;
  __syncthreads();
  for (int len = 1; len < 4096; len <<= 1) {
    #pragma unroll
    for (int q = 0; q < 2; ++q) {
      int j = q * 1024 + tid;
      int a = ((j & ~(len - 1)) << 1) | (j & (len - 1));
      float x = m1[a], y = m1[a + len];
      m1[a] = x + y; m1[a + len] = x - y;
    }
    __syncthreads();
  }
  for (int i = tid; i < 4096; i += 1024) m2[i] = m1[Pib[i]] * GGb[i];
  __syncthreads();
  for (int len = 1; len < 4096; len <<= 1) {
    #pragma unroll
    for (int q = 0; q < 2; ++q) {
      int j = q * 1024 + tid;
      int a = ((j & ~(len - 1)) << 1) | (j & (len - 1));
      float x = m2[a], y = m2[a + len];
      m2[a] = x + y; m2[a + len] = x - y;
    }
    __syncthreads();
  }
  float Sb = 0.0f;
  #pragma unroll
  for (int i = 0; i < 16; ++i) Sb += red[i];
  const float scale = 1.0f / sqrtf(Sb * 4096.0f);
  for (int i = tid; i < 4096; i += 1024) bout[i] = b0[i] + m2[i] * scale;
}

// ---- K1: per-row gather (t LDS table) + WHT_2048 along f; Sw atomic ----
__global__ __launch_bounds__(256) void k_gather_pass1(const float* __restrict__ t,
                                                      const int* __restrict__ Piw,
                                                      const float* __restrict__ GGw,
                                                      float* __restrict__ mout,
                                                      float* __restrict__ Sw) {
  __shared__ float tl[2048];
  __shared__ float row[2048];
  __shared__ float red[4];
  const int tid = threadIdx.x;
  const size_t p0 = (size_t)blockIdx.x * 2048;
  for (int i = tid; i < 2048; i += 256) tl[i] = t[i];
  __syncthreads();
  float s = 0.0f;
  #pragma unroll
  for (int q = 0; q < 8; ++q) {
    int i = q * 256 + tid;
    int pi = Piw[p0 + i];
    float g = GGw[p0 + i];
    row[i] = tl[pi & 2047] * g;
    s += g * g;
  }
  for (int off = 32; off > 0; off >>= 1) s += __shfl_down(s, off);
  if ((tid & 63) == 0) red[tid >> 6] = s;
  __syncthreads();
  if (tid == 0) atomicAdd(Sw, red[0] + red[1] + red[2] + red[3]);
  for (int len = 1; len < 2048; len <<= 1) {
    #pragma unroll
    for (int q = 0; q < 4; ++q) {
      int j = q * 256 + tid;
      int a = ((j & ~(len - 1)) << 1) | (j & (len - 1));
      float x = row[a], y = row[a + len];
      row[a] = x + y; row[a + len] = x - y;
    }
    __syncthreads();
  }
  for (int i = tid; i < 2048; i += 256) mout[p0 + i] = row[i];
}

// ---- K2a: in-register WHT_64 over o_lo (stride 2048 floats) ----
__global__ __launch_bounds__(256) void k_pass2a(float* __restrict__ m) {
  const int tg = blockIdx.x * 256 + threadIdx.x;
  const int f = tg & 2047;
  const int oh = tg >> 11;
  const size_t base = (size_t)oh * 131072 + (size_t)f;
  float v[64];
  #pragma unroll
  for (int s = 0; s < 64; ++s) v[s] = m[base + (size_t)s * 2048];
  #pragma unroll
  for (int len = 1; len < 64; len <<= 1) {
    #pragma unroll
    for (int j = 0; j < 32; ++j) {
      int a = ((j & ~(len - 1)) << 1) | (j & (len - 1));
      float x = v[a], y = v[a + len];
      v[a] = x + y; v[a + len] = x - y;
    }
  }
  #pragma unroll
  for (int s = 0; s < 64; ++s) m[base + (size_t)s * 2048] = v[s];
}

// ---- K2b: WHT_64 over o_hi (stride 131072) + epilogue W=bf16(W0+scale*m) ----
__global__ __launch_bounds__(256) void k_pass2b_epi(const float* __restrict__ m,
                                                    const float* __restrict__ W0,
                                                    const float* __restrict__ Sw,
                                                    __hip_bfloat16* __restrict__ Wb) {
  const int tg = blockIdx.x * 256 + threadIdx.x;
  const int f = tg & 2047;
  const int ol = tg >> 11;
  const size_t base = (size_t)ol * 2048 + (size_t)f;
  float v[64];
  #pragma unroll
  for (int s = 0; s < 64; ++s) v[s] = m[base + (size_t)s * 131072];
  #pragma unroll
  for (int len = 1; len < 64; len <<= 1) {
    #pragma unroll
    for (int j = 0; j < 32; ++j) {
      int a = ((j & ~(len - 1)) << 1) | (j & (len - 1));
      float x = v[a], y = v[a + len];
      v[a] = x + y; v[a + len] = x - y;
    }
  }
  const float scale = 1.0f / sqrtf((*Sw) * 8388608.0f);
  #pragma unroll
  for (int s = 0; s < 64; ++s) {
    size_t idx = base + (size_t)s * 131072;
    Wb[idx] = __float2bfloat16(W0[idx] + v[s] * scale);
  }
}

// ---- K_xcast: x (f32) -> bf16 ----
__global__ __launch_bounds__(256) void k_xcast(const float* __restrict__ x,
                                               __hip_bfloat16* __restrict__ xb) {
  const int i = (blockIdx.x * 256 + threadIdx.x) * 4;
  float4 xv = *reinterpret_cast<const float4*>(x + i);
  __hip_bfloat16 h0 = __float2bfloat16(xv.x);
  __hip_bfloat16 h1 = __float2bfloat16(xv.y);
  __hip_bfloat16 h2 = __float2bfloat16(xv.z);
  __hip_bfloat16 h3 = __float2bfloat16(xv.w);
  ushort4 pk = make_ushort4(*reinterpret_cast<unsigned short*>(&h0),
                            *reinterpret_cast<unsigned short*>(&h1),
                            *reinterpret_cast<unsigned short*>(&h2),
                            *reinterpret_cast<unsigned short*>(&h3));
  *reinterpret_cast<ushort4*>(xb + i) = pk;
}

// ---- GEMM: C[4096][4096] = A[4096][2048] * B[4096][2048]^T + bias ----
// 256x256 tile, BK=64, 8 waves (2Mx4N), 8-phase schedule, counted vmcnt,
// XOR-swizzled LDS (linear global_load_lds dest + pre-swizzled global src).
__global__ __launch_bounds__(512, 2) void k_gemm(const __hip_bfloat16* __restrict__ A,
                                                 const __hip_bfloat16* __restrict__ B,
                                                 const float* __restrict__ bias,
                                                 float* __restrict__ C) {
  constexpr int K = 2048, N = 4096, NT = K / 64;  // 32 K-tiles
  __shared__ __hip_bfloat16 As[2][256 * 64];
  __shared__ __hip_bfloat16 Bs[2][256 * 64];
  const int tid = threadIdx.x;
  const int wave = tid >> 6, lane = tid & 63;
  // XCD-aware swizzle: 256 blocks, 256 % 8 == 0 -> simple form is bijective.
  const int bid = blockIdx.x;
  const int swz = (bid & 7) * 32 + (bid >> 3);
  const int row0 = (swz & 15) * 256;
  const int col0 = (swz >> 4) * 256;
  const int wr = wave >> 2, wc = wave & 3;  // 2M x 4N wave grid
  // staging coords: 512 thr x 16B = 64 rows x 128B per issue
  const int srow = tid >> 3;                 // row in 64-row chunk
  const int gslot = (tid & 7) ^ (srow & 7);  // pre-swizzled global 16B slot
  const int ldst = tid * 8;                  // linear LDS dest (elements)

  f32x4 acc[8][4] = {};

  const int lr = lane & 15, lk = lane >> 4;

  // ---- prologue: tile0 A+B -> buf0, tile1 A -> buf1 ----
  {
    #pragma unroll
    for (int c = 0; c < 4; ++c)
      load_lds16(A + (size_t)(row0 + c * 64 + srow) * K + 0 * 64 + gslot * 8,
                 &As[0][c * 4096 + ldst]);
    #pragma unroll
    for (int c = 0; c < 4; ++c)
      load_lds16(B + (size_t)(col0 + c * 64 + srow) * K + 0 * 64 + gslot * 8,
                 &Bs[0][c * 4096 + ldst]);
    #pragma unroll
    for (int c = 0; c < 4; ++c)
      load_lds16(A + (size_t)(row0 + c * 64 + srow) * K + 1 * 64 + gslot * 8,
                 &As[1][c * 4096 + ldst]);
    VMC(4);  // tile0's 8 loads landed
    BAR();
  }

  bf16x8 a0[4][2], a1[4][2], b0[2][2], b1[2][2];

  for (int t = 0; t < NT; ++t) {
    const int cur = t & 1, nxt = cur ^ 1;
    const int tb = (t + 1 < NT) ? t + 1 : NT - 1;  // clamped (harmless re-load)
    const int ta = (t + 2 < NT) ? t + 2 : NT - 1;

    // ================= phase 1: read a0,b0 (12 ds) | stage B(t+1) half0 ====
    #pragma unroll
    for (int i = 0; i < 4; ++i)
      #pragma unroll
      for (int ks = 0; ks < 2; ++ks) {
        int row = wr * 128 + i * 16 + lr;
        int cs = ks * 4 + lk;
        a0[i][ks] = *(const bf16x8*)&As[cur][row * 64 + ((cs ^ (row & 7)) * 8)];
      }
    #pragma unroll
    for (int j = 0; j < 2; ++j)
      #pragma unroll
      for (int ks = 0; ks < 2; ++ks) {
        int row = wc * 64 + j * 16 + lr;
        int cs = ks * 4 + lk;
        b0[j][ks] = *(const bf16x8*)&Bs[cur][row * 64 + ((cs ^ (row & 7)) * 8)];
      }
    #pragma unroll
    for (int c = 0; c < 2; ++c)
      load_lds16(B + (size_t)(col0 + c * 64 + srow) * K + tb * 64 + gslot * 8,
                 &Bs[nxt][c * 4096 + ldst]);
    BAR();
    LGKM0();
    __builtin_amdgcn_s_setprio(1);
    #pragma unroll
    for (int i = 0; i < 4; ++i)
      #pragma unroll
      for (int j = 0; j < 2; ++j)
        #pragma unroll
        for (int ks = 0; ks < 2; ++ks)
          acc[i][j] = __builtin_amdgcn_mfma_f32_16x16x32_bf16(a0[i][ks], b0[j][ks], acc[i][j], 0, 0, 0);
    __builtin_amdgcn_s_setprio(0);
    BAR();

    // ================= phase 2: read a1,b1 (12 ds) | stage B(t+1) half1 ====
    #pragma unroll
    for (int i = 0; i < 4; ++i)
      #pragma unroll
      for (int ks = 0; ks < 2; ++ks) {
        int row = wr * 128 + 64 + i * 16 + lr;
        int cs = ks * 4 + lk;
        a1[i][ks] = *(const bf16x8*)&As[cur][row * 64 + ((cs ^ (row & 7)) * 8)];
      }
    #pragma unroll
    for (int j = 0; j < 2; ++j)
      #pragma unroll
      for (int ks = 0; ks < 2; ++ks) {
        int row = wc * 64 + 32 + j * 16 + lr;
        int cs = ks * 4 + lk;
        b1[j][ks] = *(const bf16x8*)&Bs[cur][row * 64 + ((cs ^ (row & 7)) * 8)];
      }
    #pragma unroll
    for (int c = 2; c < 4; ++c)
      load_lds16(B + (size_t)(col0 + c * 64 + srow) * K + tb * 64 + gslot * 8,
                 &Bs[nxt][c * 4096 + ldst]);
    BAR();
    LGKM0();
    __builtin_amdgcn_s_setprio(1);
    #pragma unroll
    for (int i = 0; i < 4; ++i)
      #pragma unroll
      for (int j = 0; j < 2; ++j)
        #pragma unroll
        for (int ks = 0; ks < 2; ++ks)
          acc[i][2 + j] = __builtin_amdgcn_mfma_f32_16x16x32_bf16(a0[i][ks], b1[j][ks], acc[i][2 + j], 0, 0, 0);
    __builtin_amdgcn_s_setprio(0);
    BAR();

    // ================= phase 3: no ds reads | stage A(t+2) half0 ===========
    #pragma unroll
    for (int c = 0; c < 2; ++c)
      load_lds16(A + (size_t)(row0 + c * 64 + srow) * K + ta * 64 + gslot * 8,
                 &As[cur][c * 4096 + ldst]);
    BAR();
    __builtin_amdgcn_s_setprio(1);
    #pragma unroll
    for (int i = 0; i < 4; ++i)
      #pragma unroll
      for (int j = 0; j < 2; ++j)
        #pragma unroll
        for (int ks = 0; ks < 2; ++ks)
          acc[4 + i][2 + j] = __builtin_amdgcn_mfma_f32_16x16x32_bf16(a1[i][ks], b1[j][ks], acc[4 + i][2 + j], 0, 0, 0);
    __builtin_amdgcn_s_setprio(0);
    BAR();

    // ================= phase 4: no ds reads | stage A(t+2) half1 | vmcnt ===
    #pragma unroll
    for (int c = 2; c < 4; ++c)
      load_lds16(A + (size_t)(row0 + c * 64 + srow) * K + ta * 64 + gslot * 8,
                 &As[cur][c * 4096 + ldst]);
    BAR();
    __builtin_amdgcn_s_setprio(1);
    #pragma unroll
    for (int i = 0; i < 4; ++i)
      #pragma unroll
      for (int j = 0; j < 2; ++j)
        #pragma unroll
        for (int ks = 0; ks < 2; ++ks)
          acc[4 + i][j] = __builtin_amdgcn_mfma_f32_16x16x32_bf16(a1[i][ks], b0[j][ks], acc[4 + i][j], 0, 0, 0);
    __builtin_amdgcn_s_setprio(0);
    VMC(4);  // everything except A(t+2) (2 half-tiles, 4 loads) has landed
    BAR();
  }

  // ---- epilogue: C = acc + bias ----
  #pragma unroll
  for (int j = 0; j < 4; ++j) {
    const int col = col0 + wc * 64 + j * 16 + lr;
    const float bv = bias[col];
    #pragma unroll
    for (int i = 0; i < 8; ++i) {
      const int row = row0 + wr * 128 + i * 16 + lk * 4;
      #pragma unroll
      for (int q = 0; q < 4; ++q)
        C[(size_t)(row + q) * N + col] = acc[i][j][q] + bv;
    }
  }
}

extern "C" void kernel_launch(void* const* d_in, const int* in_sizes, int n_in,
                              void* d_out, int out_size, void* d_ws, size_t ws_size,
                              hipStream_t stream) {
  (void)in_sizes; (void)n_in; (void)out_size; (void)ws_size;
  const float* x   = (const float*)d_in[0];
  const float* z   = (const float*)d_in[1];
  const float* W0  = (const float*)d_in[2];
  const float* b0  = (const float*)d_in[3];
  const float* BBw = (const float*)d_in[4];
  const float* GGw = (const float*)d_in[5];
  const float* BBb = (const float*)d_in[6];
  const float* GGb = (const float*)d_in[7];
  const int*   Piw = (const int*)d_in[8];
  const int*   Pib = (const int*)d_in[9];
  float* out = (float*)d_out;

  char* ws = (char*)d_ws;
  float* t_buf = (float*)(ws);                                   // 2048 f
  float* b_buf = (float*)(ws + 8192);                            // 4096 f
  float* Sw    = (float*)(ws + 24576);                           // 1 f
  float* m_buf = (float*)(ws + 32768);                           // 2^23 f (32MB)
  __hip_bfloat16* Wb = (__hip_bfloat16*)(ws + 32768 + 33554432);            // 16MB
  __hip_bfloat16* xb = (__hip_bfloat16*)(ws + 32768 + 33554432 + 16777216); // 16MB

  k_xcast<<<8192, 256, 0, stream>>>(x, xb);
  k_t<<<1, 256, 0, stream>>>(z, BBw, t_buf, Sw);
  k_bias<<<1, 1024, 0, stream>>>(z, b0, BBb, GGb, Pib, b_buf);
  k_gather_pass1<<<4096, 256, 0, stream>>>(t_buf, Piw, GGw, m_buf, Sw);
  k_pass2a<<<512, 256, 0, stream>>>(m_buf);
  k_pass2b_epi<<<512, 256, 0, stream>>>(m_buf, W0, Sw, Wb);
  k_gemm<<<256, 512, 0, stream>>>(xb, Wb, b_buf, out);
}

// Round 3
// 188.762 us; speedup vs baseline: 1.1748x; 1.0601x over previous
//
#include <hip/hip_runtime.h>
#include <hip/hip_bf16.h>
#include <math.h>

typedef __bf16  bf16x8 __attribute__((ext_vector_type(8)));
typedef float   f32x4  __attribute__((ext_vector_type(4)));

// ---------------- helpers ----------------
static __device__ __forceinline__ void load_lds16(const void* g, void* l) {
  __builtin_amdgcn_global_load_lds(
      (const __attribute__((address_space(1))) void*)(g),
      (__attribute__((address_space(3))) void*)(l), 16, 0, 0);
}

#define BAR() __builtin_amdgcn_s_barrier()
#define SB0() __builtin_amdgcn_sched_barrier(0)
#define LGKM(N) do { asm volatile("s_waitcnt lgkmcnt(" #N ")" ::: "memory"); SB0(); } while (0)
#define VMC(N) asm volatile("s_waitcnt vmcnt(" #N ")" ::: "memory")

// ---- K_t_bias: t = WHT_2048(BB_w[:2048] * z); Sw = 0; bias fastfood ----
__global__ __launch_bounds__(1024) void k_t_bias(const float* __restrict__ z,
                                                 const float* __restrict__ BBw,
                                                 const float* __restrict__ b0,
                                                 const float* __restrict__ BBb,
                                                 const float* __restrict__ GGb,
                                                 const int* __restrict__ Pib,
                                                 float* __restrict__ t_out,
                                                 float* __restrict__ bout,
                                                 float* __restrict__ Sw) {
  __shared__ float u[2048];
  __shared__ float m1[4096];
  __shared__ float m2[4096];
  __shared__ float red[16];
  const int tid = threadIdx.x;
  // --- t part ---
  for (int i = tid; i < 2048; i += 1024) u[i] = BBw[i] * z[i];
  // --- bias init ---
  for (int i = tid; i < 4096; i += 1024)
    m1[i] = (i < 2048) ? BBb[i] * z[i] : 0.0f;
  float s = 0.0f;
  for (int i = tid; i < 4096; i += 1024) { float g = GGb[i]; s += g * g; }
  for (int off = 32; off > 0; off >>= 1) s += __shfl_down(s, off);
  if ((tid & 63) == 0) red[tid >> 6] = s;
  __syncthreads();
  // t butterflies (1024 pairs/stage) + bias first WHT (2048 pairs/stage)
  for (int len = 1; len < 2048; len <<= 1) {
    if (tid < 1024) {
      int j = tid;
      int a = ((j & ~(len - 1)) << 1) | (j & (len - 1));
      float x = u[a], y = u[a + len];
      u[a] = x + y; u[a + len] = x - y;
    }
    #pragma unroll
    for (int q = 0; q < 2; ++q) {
      int j = q * 1024 + tid;
      int a = ((j & ~(len - 1)) << 1) | (j & (len - 1));
      float x = m1[a], y = m1[a + len];
      m1[a] = x + y; m1[a + len] = x - y;
    }
    __syncthreads();
  }
  { // last bias stage (len = 2048)
    int len = 2048;
    #pragma unroll
    for (int q = 0; q < 2; ++q) {
      int j = q * 1024 + tid;
      int a = ((j & ~(len - 1)) << 1) | (j & (len - 1));
      float x = m1[a], y = m1[a + len];
      m1[a] = x + y; m1[a + len] = x - y;
    }
    __syncthreads();
  }
  for (int i = tid; i < 2048; i += 1024) t_out[i] = u[i];
  if (tid == 0) *Sw = 0.0f;
  for (int i = tid; i < 4096; i += 1024) m2[i] = m1[Pib[i]] * GGb[i];
  __syncthreads();
  for (int len = 1; len < 4096; len <<= 1) {
    #pragma unroll
    for (int q = 0; q < 2; ++q) {
      int j = q * 1024 + tid;
      int a = ((j & ~(len - 1)) << 1) | (j & (len - 1));
      float x = m2[a], y = m2[a + len];
      m2[a] = x + y; m2[a + len] = x - y;
    }
    __syncthreads();
  }
  float Sb = 0.0f;
  #pragma unroll
  for (int i = 0; i < 16; ++i) Sb += red[i];
  const float scale = 1.0f / sqrtf(Sb * 4096.0f);
  for (int i = tid; i < 4096; i += 1024) bout[i] = b0[i] + m2[i] * scale;
}

// ---- K1: per-row gather (t LDS table) + WHT_2048 along f; bf16 out ----
__global__ __launch_bounds__(256) void k_gather_pass1(const float* __restrict__ t,
                                                      const int* __restrict__ Piw,
                                                      const float* __restrict__ GGw,
                                                      __hip_bfloat16* __restrict__ mout,
                                                      float* __restrict__ Sw) {
  __shared__ float tl[2048];
  __shared__ float row[2048];
  __shared__ float red[4];
  const int tid = threadIdx.x;
  const size_t p0 = (size_t)blockIdx.x * 2048;
  for (int i = tid; i < 2048; i += 256) tl[i] = t[i];
  __syncthreads();
  float s = 0.0f;
  #pragma unroll
  for (int q = 0; q < 8; ++q) {
    int i = q * 256 + tid;
    int pi = Piw[p0 + i];
    float g = GGw[p0 + i];
    row[i] = tl[pi & 2047] * g;
    s += g * g;
  }
  for (int off = 32; off > 0; off >>= 1) s += __shfl_down(s, off);
  if ((tid & 63) == 0) red[tid >> 6] = s;
  __syncthreads();
  if (tid == 0) atomicAdd(Sw, red[0] + red[1] + red[2] + red[3]);
  for (int len = 1; len < 2048; len <<= 1) {
    #pragma unroll
    for (int q = 0; q < 4; ++q) {
      int j = q * 256 + tid;
      int a = ((j & ~(len - 1)) << 1) | (j & (len - 1));
      float x = row[a], y = row[a + len];
      row[a] = x + y; row[a + len] = x - y;
    }
    __syncthreads();
  }
  for (int i = tid; i < 2048; i += 256)
    mout[p0 + i] = __float2bfloat16(row[i]);
}

// ---- K2a: in-register WHT_64 over o_lo (stride 2048), bf16 in/out ----
__global__ __launch_bounds__(256) void k_pass2a(__hip_bfloat16* __restrict__ m) {
  const int tg = blockIdx.x * 256 + threadIdx.x;
  const int f = tg & 2047;
  const int oh = tg >> 11;
  const size_t base = (size_t)oh * 131072 + (size_t)f;
  float v[64];
  #pragma unroll
  for (int s = 0; s < 64; ++s) v[s] = __bfloat162float(m[base + (size_t)s * 2048]);
  #pragma unroll
  for (int len = 1; len < 64; len <<= 1) {
    #pragma unroll
    for (int j = 0; j < 32; ++j) {
      int a = ((j & ~(len - 1)) << 1) | (j & (len - 1));
      float x = v[a], y = v[a + len];
      v[a] = x + y; v[a + len] = x - y;
    }
  }
  #pragma unroll
  for (int s = 0; s < 64; ++s) m[base + (size_t)s * 2048] = __float2bfloat16(v[s]);
}

// ---- K2b: WHT_64 over o_hi (stride 131072) + epilogue W=bf16(W0+scale*m) ----
__global__ __launch_bounds__(256) void k_pass2b_epi(const __hip_bfloat16* __restrict__ m,
                                                    const float* __restrict__ W0,
                                                    const float* __restrict__ Sw,
                                                    __hip_bfloat16* __restrict__ Wb) {
  const int tg = blockIdx.x * 256 + threadIdx.x;
  const int f = tg & 2047;
  const int ol = tg >> 11;
  const size_t base = (size_t)ol * 2048 + (size_t)f;
  float v[64];
  #pragma unroll
  for (int s = 0; s < 64; ++s) v[s] = __bfloat162float(m[base + (size_t)s * 131072]);
  #pragma unroll
  for (int len = 1; len < 64; len <<= 1) {
    #pragma unroll
    for (int j = 0; j < 32; ++j) {
      int a = ((j & ~(len - 1)) << 1) | (j & (len - 1));
      float x = v[a], y = v[a + len];
      v[a] = x + y; v[a + len] = x - y;
    }
  }
  const float scale = 1.0f / sqrtf((*Sw) * 8388608.0f);
  #pragma unroll
  for (int s = 0; s < 64; ++s) {
    size_t idx = base + (size_t)s * 131072;
    Wb[idx] = __float2bfloat16(W0[idx] + v[s] * scale);
  }
}

// ---- K_xcast: x (f32) -> bf16 ----
__global__ __launch_bounds__(256) void k_xcast(const float* __restrict__ x,
                                               __hip_bfloat16* __restrict__ xb) {
  const int i = (blockIdx.x * 256 + threadIdx.x) * 4;
  float4 xv = *reinterpret_cast<const float4*>(x + i);
  __hip_bfloat16 h0 = __float2bfloat16(xv.x);
  __hip_bfloat16 h1 = __float2bfloat16(xv.y);
  __hip_bfloat16 h2 = __float2bfloat16(xv.z);
  __hip_bfloat16 h3 = __float2bfloat16(xv.w);
  ushort4 pk = make_ushort4(*reinterpret_cast<unsigned short*>(&h0),
                            *reinterpret_cast<unsigned short*>(&h1),
                            *reinterpret_cast<unsigned short*>(&h2),
                            *reinterpret_cast<unsigned short*>(&h3));
  *reinterpret_cast<ushort4*>(xb + i) = pk;
}

// ---- GEMM: C[4096][4096] = A[4096][2048] * B[4096][2048]^T + bias ----
// 256x256 tile, BK=64, 8 waves (2Mx4N), 4-phase schedule with one-phase
// read lookahead, deep staging (B t+1 @ph1, A t+2 @ph4), counted vmcnt.
__global__ __launch_bounds__(512, 2) void k_gemm(const __hip_bfloat16* __restrict__ A,
                                                 const __hip_bfloat16* __restrict__ B,
                                                 const float* __restrict__ bias,
                                                 float* __restrict__ C) {
  constexpr int K = 2048, N = 4096, NT = K / 64;  // 32 K-tiles
  __shared__ __hip_bfloat16 As[2][256 * 64];
  __shared__ __hip_bfloat16 Bs[2][256 * 64];
  const int tid = threadIdx.x;
  const int wave = tid >> 6, lane = tid & 63;
  const int bid = blockIdx.x;
  const int swz = (bid & 7) * 32 + (bid >> 3);   // 256 % 8 == 0 -> bijective
  const int row0 = (swz & 15) * 256;
  const int col0 = (swz >> 4) * 256;
  const int wr = wave >> 2, wc = wave & 3;       // 2M x 4N wave grid
  const int srow = tid >> 3;                     // row in 64-row chunk
  const int gslot = (tid & 7) ^ (srow & 7);      // pre-swizzled global slot
  const int ldst = tid * 8;                      // linear LDS dest (elements)
  const int lr = lane & 15, lk = lane >> 4;

  f32x4 acc[8][4] = {};

  // ---- prologue: A(0),B(0) -> buf0; A(1) -> buf1 ----
  #pragma unroll
  for (int c = 0; c < 4; ++c)
    load_lds16(A + (size_t)(row0 + c * 64 + srow) * K + 0 * 64 + gslot * 8,
               &As[0][c * 4096 + ldst]);
  #pragma unroll
  for (int c = 0; c < 4; ++c)
    load_lds16(B + (size_t)(col0 + c * 64 + srow) * K + 0 * 64 + gslot * 8,
               &Bs[0][c * 4096 + ldst]);
  #pragma unroll
  for (int c = 0; c < 4; ++c)
    load_lds16(A + (size_t)(row0 + c * 64 + srow) * K + 1 * 64 + gslot * 8,
               &As[1][c * 4096 + ldst]);
  VMC(4);
  BAR();

  bf16x8 a0[4][2], a1[4][2], b0[2][2], b1[2][2];

  for (int t = 0; t < NT; ++t) {
    const int cur = t & 1, nxt = cur ^ 1;
    const int tb = (t + 1 < NT) ? t + 1 : NT - 1;
    const int ta = (t + 2 < NT) ? t + 2 : NT - 1;

    // ========== phase 1: read a0,b0 (this phase) + b1 (lookahead) ==========
    #pragma unroll
    for (int i = 0; i < 4; ++i)
      #pragma unroll
      for (int ks = 0; ks < 2; ++ks) {
        int row = wr * 128 + i * 16 + lr;
        a0[i][ks] = *(const bf16x8*)&As[cur][row * 64 + (((ks * 4 + lk) ^ (row & 7)) * 8)];
      }
    #pragma unroll
    for (int j = 0; j < 2; ++j)
      #pragma unroll
      for (int ks = 0; ks < 2; ++ks) {
        int row = wc * 64 + j * 16 + lr;
        b0[j][ks] = *(const bf16x8*)&Bs[cur][row * 64 + (((ks * 4 + lk) ^ (row & 7)) * 8)];
      }
    SB0();  // pin: a0/b0 issued before b1
    #pragma unroll
    for (int j = 0; j < 2; ++j)
      #pragma unroll
      for (int ks = 0; ks < 2; ++ks) {
        int row = wc * 64 + 32 + j * 16 + lr;
        b1[j][ks] = *(const bf16x8*)&Bs[cur][row * 64 + (((ks * 4 + lk) ^ (row & 7)) * 8)];
      }
    SB0();  // pin: b1 issued before staging
    #pragma unroll
    for (int c = 0; c < 4; ++c)   // stage B(t+1) -> Bs[nxt] (safe: B(t-1) reads long retired)
      load_lds16(B + (size_t)(col0 + c * 64 + srow) * K + tb * 64 + gslot * 8,
                 &Bs[nxt][c * 4096 + ldst]);
    BAR();
    LGKM(4);  // a0,b0 done; b1 may fly
    __builtin_amdgcn_s_setprio(1);
    #pragma unroll
    for (int i = 0; i < 4; ++i)
      #pragma unroll
      for (int j = 0; j < 2; ++j)
        #pragma unroll
        for (int ks = 0; ks < 2; ++ks)
          acc[i][j] = __builtin_amdgcn_mfma_f32_16x16x32_bf16(a0[i][ks], b0[j][ks], acc[i][j], 0, 0, 0);
    __builtin_amdgcn_s_setprio(0);
    BAR();

    // ========== phase 2: read a1 (lookahead); MFMA q01 = a0 x b1 ==========
    #pragma unroll
    for (int i = 0; i < 4; ++i)
      #pragma unroll
      for (int ks = 0; ks < 2; ++ks) {
        int row = wr * 128 + 64 + i * 16 + lr;
        a1[i][ks] = *(const bf16x8*)&As[cur][row * 64 + (((ks * 4 + lk) ^ (row & 7)) * 8)];
      }
    SB0();
    BAR();
    LGKM(8);  // b1 done; a1 may fly
    __builtin_amdgcn_s_setprio(1);
    #pragma unroll
    for (int i = 0; i < 4; ++i)
      #pragma unroll
      for (int j = 0; j < 2; ++j)
        #pragma unroll
        for (int ks = 0; ks < 2; ++ks)
          acc[i][2 + j] = __builtin_amdgcn_mfma_f32_16x16x32_bf16(a0[i][ks], b1[j][ks], acc[i][2 + j], 0, 0, 0);
    __builtin_amdgcn_s_setprio(0);
    BAR();

    // ========== phase 3: MFMA q11 = a1 x b1 (a1 must be done) ==========
    LGKM(0);
    __builtin_amdgcn_s_setprio(1);
    #pragma unroll
    for (int i = 0; i < 4; ++i)
      #pragma unroll
      for (int j = 0; j < 2; ++j)
        #pragma unroll
        for (int ks = 0; ks < 2; ++ks)
          acc[4 + i][2 + j] = __builtin_amdgcn_mfma_f32_16x16x32_bf16(a1[i][ks], b1[j][ks], acc[4 + i][2 + j], 0, 0, 0);
    __builtin_amdgcn_s_setprio(0);
    BAR();  // all waves retired a1 reads from As[cur] -> ph4 staging safe

    // ========== phase 4: stage A(t+2) -> As[cur]; MFMA q10; vmcnt gate ====
    #pragma unroll
    for (int c = 0; c < 4; ++c)
      load_lds16(A + (size_t)(row0 + c * 64 + srow) * K + ta * 64 + gslot * 8,
                 &As[cur][c * 4096 + ldst]);
    SB0();
    __builtin_amdgcn_s_setprio(1);
    #pragma unroll
    for (int i = 0; i < 4; ++i)
      #pragma unroll
      for (int j = 0; j < 2; ++j)
        #pragma unroll
        for (int ks = 0; ks < 2; ++ks)
          acc[4 + i][j] = __builtin_amdgcn_mfma_f32_16x16x32_bf16(a1[i][ks], b0[j][ks], acc[4 + i][j], 0, 0, 0);
    __builtin_amdgcn_s_setprio(0);
    VMC(4);  // drain through B(t+1); A(t+2)'s 4 loads stay in flight
    BAR();
  }

  // ---- epilogue: C = acc + bias ----
  #pragma unroll
  for (int j = 0; j < 4; ++j) {
    const int col = col0 + wc * 64 + j * 16 + lr;
    const float bv = bias[col];
    #pragma unroll
    for (int i = 0; i < 8; ++i) {
      const int row = row0 + wr * 128 + i * 16 + lk * 4;
      #pragma unroll
      for (int q = 0; q < 4; ++q)
        C[(size_t)(row + q) * N + col] = acc[i][j][q] + bv;
    }
  }
}

extern "C" void kernel_launch(void* const* d_in, const int* in_sizes, int n_in,
                              void* d_out, int out_size, void* d_ws, size_t ws_size,
                              hipStream_t stream) {
  (void)in_sizes; (void)n_in; (void)out_size; (void)ws_size;
  const float* x   = (const float*)d_in[0];
  const float* z   = (const float*)d_in[1];
  const float* W0  = (const float*)d_in[2];
  const float* b0  = (const float*)d_in[3];
  const float* BBw = (const float*)d_in[4];
  const float* GGw = (const float*)d_in[5];
  const float* BBb = (const float*)d_in[6];
  const float* GGb = (const float*)d_in[7];
  const int*   Piw = (const int*)d_in[8];
  const int*   Pib = (const int*)d_in[9];
  float* out = (float*)d_out;

  char* ws = (char*)d_ws;
  float* t_buf = (float*)(ws);                                   // 2048 f
  float* b_buf = (float*)(ws + 8192);                            // 4096 f
  float* Sw    = (float*)(ws + 24576);                           // 1 f
  __hip_bfloat16* m_buf = (__hip_bfloat16*)(ws + 32768);                    // 2^23 bf16 (16MB)
  __hip_bfloat16* Wb = (__hip_bfloat16*)(ws + 32768 + 16777216);            // 16MB
  __hip_bfloat16* xb = (__hip_bfloat16*)(ws + 32768 + 16777216 + 16777216); // 16MB

  k_xcast<<<8192, 256, 0, stream>>>(x, xb);
  k_t_bias<<<1, 1024, 0, stream>>>(z, BBw, b0, BBb, GGb, Pib, t_buf, b_buf, Sw);
  k_gather_pass1<<<4096, 256, 0, stream>>>(t_buf, Piw, GGw, m_buf, Sw);
  k_pass2a<<<512, 256, 0, stream>>>(m_buf);
  k_pass2b_epi<<<512, 256, 0, stream>>>(m_buf, W0, Sw, Wb);
  k_gemm<<<256, 512, 0, stream>>>(xb, Wb, b_buf, out);
}